// Round 1
// baseline (4863.755 us; speedup 1.0000x reference)
//
#include <hip/hip_runtime.h>
#include <math.h>

#define B_  64
#define T_  256
#define NIN 128
#define NH  2048

// ws layout: mem_d (B*NH double, 1 MB) | sp0 (B*NH float) | sp1 (B*NH float)

__global__ __launch_bounds__(256) void init_kernel(const float* __restrict__ mem0,
                                                   double* __restrict__ mem_d,
                                                   float* __restrict__ sp0) {
    int idx = blockIdx.x * 256 + threadIdx.x;
    if (idx < B_ * NH) {
        mem_d[idx] = (double)mem0[idx];
        sp0[idx] = 0.0f;
    }
}

// grid: 512 blocks x 256 threads. block = (b-quad, 64-col group), wave = 1 batch x 64 cols.
// XCD swizzle: col-group = (bid%8)*4 + (bid/8)%4 so each XCD's A column slice (2 MB) stays L2-resident.
__global__ __launch_bounds__(256) void step_kernel(
    const float* __restrict__ x,      // [B,T,NIN]
    const float* __restrict__ W_in,   // [NIN,NH]
    const float* __restrict__ A,      // [NH,NH]
    const float* __restrict__ bias,   // [NH]
    double* __restrict__ mem_d,       // [B,NH]
    const float* __restrict__ sp_rd,  // [B,NH] spikes at t-1 (0.0/1.0)
    float* __restrict__ sp_wr,        // [B,NH] spikes at t
    float* __restrict__ out_mem,      // [B,T,NH]
    float* __restrict__ out_spk,      // [B,T,NH]
    int t)
{
    __shared__ unsigned short lists[4][NH];

    const int tid  = threadIdx.x;
    const int w    = tid >> 6;        // wave id in block (0..3)
    const int lane = tid & 63;

    const int bid    = blockIdx.x;    // [0,512)
    const int xcd    = bid & 7;
    const int within = bid >> 3;      // [0,64)
    const int sub    = within & 3;
    const int bq     = within >> 2;   // [0,16)
    const int cg     = xcd * 4 + sub; // [0,32)
    const int col    = cg * 64 + lane;
    const int b      = bq * 4 + w;    // [0,64)

    const float* __restrict__ sprow = sp_rd + (size_t)b * NH;

    // ---- Phase 1: build compacted active-row list for batch b (wave-private) ----
    int n = 0;
    const unsigned long long ltm = (1ull << lane) - 1ull;
    for (int base = 0; base < NH; base += 64) {
        float s = sprow[base + lane];
        bool on = (s > 0.5f);
        unsigned long long m = __ballot(on);
        if (on) {
            int pos = n + __popcll(m & ltm);
            lists[w][pos] = (unsigned short)(base + lane);
        }
        n += __popcll(m);
    }

    // ---- Phase 2: U = x_t[b] . W_in[:,col]  (fp64 accumulate) ----
    const float* __restrict__ xrow = x + ((size_t)b * T_ + t) * NIN;
    double u0 = 0.0, u1 = 0.0;
#pragma unroll 4
    for (int k = 0; k < NIN; k += 2) {
        u0 += (double)xrow[k]     * (double)W_in[(size_t)k * NH + col];
        u1 += (double)xrow[k + 1] * (double)W_in[(size_t)(k + 1) * NH + col];
    }
    const double u = u0 + u1;

    // ---- Phase 3: r = sum of active rows of A at this column (fp64) ----
    double r0 = 0.0, r1 = 0.0, r2 = 0.0, r3 = 0.0;
    int k = 0;
    for (; k + 4 <= n; k += 4) {
        int i0 = lists[w][k];
        int i1 = lists[w][k + 1];
        int i2 = lists[w][k + 2];
        int i3 = lists[w][k + 3];
        r0 += (double)A[(size_t)i0 * NH + col];
        r1 += (double)A[(size_t)i1 * NH + col];
        r2 += (double)A[(size_t)i2 * NH + col];
        r3 += (double)A[(size_t)i3 * NH + col];
    }
    for (; k < n; ++k) {
        r0 += (double)A[(size_t)lists[w][k] * NH + col];
    }
    const double r = (r0 + r1) + (r2 + r3);

    // ---- Phase 4: activation, membrane update, spike, outputs ----
    const double pre = 0.5 * (u + (double)bias[col]);   // (1-ALPHA)*(U+bias), ALPHA=0.5
    const double y   = tanh(0.5 * r + pre);             // tanh(ALPHA*r + ...)

    const size_t mi = (size_t)b * NH + col;
    double m = mem_d[mi];
    const double sp_prev = (double)sprow[col];           // exactly 0.0 or 1.0
    m = m * 0.5 - 0.5 * (1.0 - sp_prev) + y;             // DECAY=0.5, THR=0.5
    const double snew = (m > 0.5) ? 1.0 : 0.0;

    mem_d[mi] = m;
    sp_wr[mi] = (float)snew;

    const size_t oi = ((size_t)b * T_ + t) * NH + col;
    out_mem[oi] = (float)m;
    out_spk[oi] = (float)snew;
}

extern "C" void kernel_launch(void* const* d_in, const int* in_sizes, int n_in,
                              void* d_out, int out_size, void* d_ws, size_t ws_size,
                              hipStream_t stream) {
    const float* x     = (const float*)d_in[0];
    const float* W_in  = (const float*)d_in[1];
    const float* A     = (const float*)d_in[2];
    const float* bias  = (const float*)d_in[3];
    const float* mem0  = (const float*)d_in[4];

    float* out_mem = (float*)d_out;                       // [1,B,T,NH]
    float* out_spk = out_mem + (size_t)B_ * T_ * NH;      // [1,B,T,NH]

    char* ws = (char*)d_ws;
    double* mem_d = (double*)ws;
    float*  sp0   = (float*)(ws + (size_t)B_ * NH * sizeof(double));
    float*  sp1   = sp0 + (size_t)B_ * NH;

    hipLaunchKernelGGL(init_kernel, dim3((B_ * NH + 255) / 256), dim3(256), 0, stream,
                       mem0, mem_d, sp0);

    for (int t = 0; t < T_; ++t) {
        const float* rd = (t & 1) ? sp1 : sp0;
        float*       wr = (t & 1) ? sp0 : sp1;
        hipLaunchKernelGGL(step_kernel, dim3(512), dim3(256), 0, stream,
                           x, W_in, A, bias, mem_d, rd, wr, out_mem, out_spk, t);
    }
}